// Round 3
// baseline (472.730 us; speedup 1.0000x reference)
//
#include <hip/hip_runtime.h>

#define HH 16
#define SS 4096
#define DHD 128
#define BR 128        // q rows per block (32 per wave)
#define BC 64         // k/v rows per tile
#define LDQ 136       // row length (bf16) for q_s/k_s: 272B, 16B-aligned, +pad
#define LDV 68        // row length for vt_s: 136B = 34 banks (write floor)
#define LDP 72        // row length for p_s
#define DM  (HH * DHD)

typedef __bf16 bf16x8_t __attribute__((ext_vector_type(8)));
typedef __bf16 bf16x4_t __attribute__((ext_vector_type(4)));
typedef float  f32x4_t  __attribute__((ext_vector_type(4)));

// ---------------- Phase 1: partial flash attention over a K-half ----------------
__global__ __launch_bounds__(256, 2)
void fa_part(const float* __restrict__ q, const float* __restrict__ k,
             const float* __restrict__ v, float* __restrict__ out,
             float* __restrict__ wsO, float2* __restrict__ ml0,
             float2* __restrict__ ml1)
{
    // LPT item order: qt descends with blockIdx so long items dispatch first.
    const int b    = blockIdx.x;
    const int qt   = 31 - (b >> 5);
    const int h    = (b >> 1) & 15;
    const int half = b & 1;
    const int jbeg = half ? (qt + 1) : 0;
    const int jend = jbeg + qt + 1;          // exclusive; both halves equal length

    const int tid  = threadIdx.x;
    const int wave = tid >> 6;
    const int lane = tid & 63;
    const int l16  = lane & 15;
    const int quad = lane >> 4;
    const int rK   = tid >> 5;               // staging row base (0..7)
    const int c4   = tid & 31;               // staging float4 col
    const int dbase = (wave & 1) * 64;       // V-transpose staging split
    const int rbase = (wave >> 1) * 32;

    __shared__ __align__(16) unsigned short qp_s[BR * LDQ];  // Q staging, then P scratch
    __shared__ __align__(16) unsigned short k_s [BC * LDQ];
    __shared__ __align__(16) unsigned short vt_s[DHD * LDV]; // vt_s[d][s]

    const size_t hoff = (size_t)h * SS * DHD;
    const float* qh = q + hoff;
    const float* kh = k + hoff;
    const float* vh = v + hoff;

    float4 kreg[8];
    float  vreg[8][4];
    auto issue = [&](int j) {
        const float* kb = kh + (size_t)j * BC * DHD;
        #pragma unroll
        for (int i = 0; i < 8; ++i)
            kreg[i] = ((const float4*)(kb + (size_t)(rK + i * 8) * DHD))[c4];
        const float* vb = vh + (size_t)j * BC * DHD + dbase + lane;
        #pragma unroll
        for (int p = 0; p < 8; ++p) {
            const float* vp = vb + (size_t)(rbase + p * 4) * DHD;
            vreg[p][0] = vp[0];
            vreg[p][1] = vp[DHD];
            vreg[p][2] = vp[2 * DHD];
            vreg[p][3] = vp[3 * DHD];
        }
    };

    const float scale = 0.088388347648318447f;   // 1/sqrt(128), folded into Q

    issue(jbeg);

    // ---- stage Q tile (scale folded) ----
    #pragma unroll
    for (int i = 0; i < 16; ++i) {
        int idx = tid + i * 256;           // 0..4095
        int r   = idx >> 5;
        int cc  = idx & 31;
        float4 val = ((const float4*)(qh + (size_t)(qt * BR + r) * DHD))[cc];
        bf16x4_t bb;
        bb[0] = (__bf16)(val.x * scale); bb[1] = (__bf16)(val.y * scale);
        bb[2] = (__bf16)(val.z * scale); bb[3] = (__bf16)(val.w * scale);
        *(bf16x4_t*)&qp_s[r * LDQ + cc * 4] = bb;
    }
    __syncthreads();

    // ---- Q A-fragments: wave owns rows wave*32 .. +32 ----
    bf16x8_t qf[2][4];
    #pragma unroll
    for (int mt = 0; mt < 2; ++mt)
        #pragma unroll
        for (int kc = 0; kc < 4; ++kc)
            qf[mt][kc] = *(const bf16x8_t*)
                &qp_s[(wave * 32 + mt * 16 + l16) * LDQ + kc * 32 + quad * 8];

    f32x4_t oacc[2][8];
    #pragma unroll
    for (int mt = 0; mt < 2; ++mt)
        #pragma unroll
        for (int fo = 0; fo < 8; ++fo) oacc[mt][fo] = (f32x4_t)(0.0f);
    float mi[2][4], li[2][4];
    #pragma unroll
    for (int mt = 0; mt < 2; ++mt)
        #pragma unroll
        for (int r = 0; r < 4; ++r) { mi[mt][r] = -INFINITY; li[mt][r] = 0.0f; }

    for (int j = jbeg; j < jend; ++j) {
        __syncthreads();               // prev-iter LDS reads done; qf loaded
        // ---- commit prefetched K ----
        #pragma unroll
        for (int i = 0; i < 8; ++i) {
            bf16x4_t bb;
            bb[0] = (__bf16)kreg[i].x; bb[1] = (__bf16)kreg[i].y;
            bb[2] = (__bf16)kreg[i].z; bb[3] = (__bf16)kreg[i].w;
            *(bf16x4_t*)&k_s[(rK + i * 8) * LDQ + c4 * 4] = bb;
        }
        // ---- commit prefetched V transposed ----
        #pragma unroll
        for (int p = 0; p < 8; ++p) {
            bf16x4_t bb;
            bb[0] = (__bf16)vreg[p][0]; bb[1] = (__bf16)vreg[p][1];
            bb[2] = (__bf16)vreg[p][2]; bb[3] = (__bf16)vreg[p][3];
            *(bf16x4_t*)&vt_s[(dbase + lane) * LDV + rbase + p * 4] = bb;
        }
        if (j + 1 < jend) issue(j + 1);
        __syncthreads();

        // ---- S = Q K^T : per wave 32x64, K-frags reused across 2 m-tiles ----
        f32x4_t sa[2][4];
        #pragma unroll
        for (int mt = 0; mt < 2; ++mt)
            #pragma unroll
            for (int n = 0; n < 4; ++n) sa[mt][n] = (f32x4_t)(0.0f);
        #pragma unroll
        for (int kc = 0; kc < 4; ++kc)
            #pragma unroll
            for (int n = 0; n < 4; ++n) {
                bf16x8_t bf = *(const bf16x8_t*)
                    &k_s[(n * 16 + l16) * LDQ + kc * 32 + quad * 8];
                sa[0][n] = __builtin_amdgcn_mfma_f32_16x16x32_bf16(qf[0][kc], bf, sa[0][n], 0, 0, 0);
                sa[1][n] = __builtin_amdgcn_mfma_f32_16x16x32_bf16(qf[1][kc], bf, sa[1][n], 0, 0, 0);
            }

        // ---- causal mask + online softmax (scale already in Q) ----
        const bool nm = (j >= 2 * qt);
        float alpha[2][4];
        #pragma unroll
        for (int mt = 0; mt < 2; ++mt)
            #pragma unroll
            for (int r = 0; r < 4; ++r) {
                if (nm) {
                    int grow = wave * 32 + mt * 16 + quad * 4 + r;
                    int gc0  = (j - 2 * qt) * 64 + l16;
                    #pragma unroll
                    for (int n = 0; n < 4; ++n)
                        if (gc0 + n * 16 > grow) sa[mt][n][r] = -INFINITY;
                }
                float mx = fmaxf(fmaxf(sa[mt][0][r], sa[mt][1][r]),
                                 fmaxf(sa[mt][2][r], sa[mt][3][r]));
                mx = fmaxf(mx, __shfl_xor(mx, 1));
                mx = fmaxf(mx, __shfl_xor(mx, 2));
                mx = fmaxf(mx, __shfl_xor(mx, 4));
                mx = fmaxf(mx, __shfl_xor(mx, 8));
                // floor avoids exp(-inf - -inf)=NaN on fully-masked rows (qt=0 half1)
                float mnew = fmaxf(fmaxf(mi[mt][r], mx), -1.0e30f);
                float a = __expf(mi[mt][r] - mnew);
                mi[mt][r] = fmaxf(mi[mt][r], mx);
                float rs = 0.0f;
                #pragma unroll
                for (int n = 0; n < 4; ++n) {
                    float pv = __expf(sa[mt][n][r] - mnew);
                    sa[mt][n][r] = pv;
                    rs += pv;
                }
                rs += __shfl_xor(rs, 1);
                rs += __shfl_xor(rs, 2);
                rs += __shfl_xor(rs, 4);
                rs += __shfl_xor(rs, 8);
                li[mt][r] = li[mt][r] * a + rs;
                alpha[mt][r] = a;
            }

        // ---- P -> LDS (C->A layout), rescale O ----
        #pragma unroll
        for (int mt = 0; mt < 2; ++mt)
            #pragma unroll
            for (int n = 0; n < 4; ++n)
                #pragma unroll
                for (int r = 0; r < 4; ++r)
                    ((__bf16*)qp_s)[(wave * 32 + mt * 16 + quad * 4 + r) * LDP + n * 16 + l16] =
                        (__bf16)sa[mt][n][r];

        #pragma unroll
        for (int mt = 0; mt < 2; ++mt)
            #pragma unroll
            for (int fo = 0; fo < 8; ++fo)
                #pragma unroll
                for (int r = 0; r < 4; ++r)
                    oacc[mt][fo][r] *= alpha[mt][r];

        // ---- O += P V (V-frags reused across 2 m-tiles) ----
        #pragma unroll
        for (int kc = 0; kc < 2; ++kc) {
            bf16x8_t pa0 = *(const bf16x8_t*)
                &qp_s[(wave * 32 + l16) * LDP + kc * 32 + quad * 8];
            bf16x8_t pa1 = *(const bf16x8_t*)
                &qp_s[(wave * 32 + 16 + l16) * LDP + kc * 32 + quad * 8];
            #pragma unroll
            for (int fo = 0; fo < 8; ++fo) {
                bf16x4_t blo = *(const bf16x4_t*)
                    &vt_s[(fo * 16 + l16) * LDV + kc * 32 + quad * 8];
                bf16x4_t bhi = *(const bf16x4_t*)
                    &vt_s[(fo * 16 + l16) * LDV + kc * 32 + quad * 8 + 4];
                bf16x8_t bf = __builtin_shufflevector(blo, bhi, 0,1,2,3,4,5,6,7);
                oacc[0][fo] = __builtin_amdgcn_mfma_f32_16x16x32_bf16(pa0, bf, oacc[0][fo], 0, 0, 0);
                oacc[1][fo] = __builtin_amdgcn_mfma_f32_16x16x32_bf16(pa1, bf, oacc[1][fo], 0, 0, 0);
            }
        }
    }

    // ---- epilogue: write UNNORMALIZED partial O + (m, l) per row ----
    float* dstO = half ? wsO : out;
    float2* ml  = half ? ml1 : ml0;
    #pragma unroll
    for (int mt = 0; mt < 2; ++mt) {
        #pragma unroll
        for (int r = 0; r < 4; ++r) {
            int grow = qt * BR + wave * 32 + mt * 16 + quad * 4 + r;
            if (l16 == 0) ml[grow * HH + h] = make_float2(mi[mt][r], li[mt][r]);
        }
        #pragma unroll
        for (int fo = 0; fo < 8; ++fo)
            #pragma unroll
            for (int r = 0; r < 4; ++r) {
                int grow = qt * BR + wave * 32 + mt * 16 + quad * 4 + r;
                dstO[(size_t)grow * DM + h * DHD + fo * 16 + l16] = oacc[mt][fo][r];
            }
    }
}

// ---------------- Phase 2: merge the two K-halves ----------------
__global__ __launch_bounds__(256)
void fa_merge(float* __restrict__ out, const float* __restrict__ wsO,
              const float2* __restrict__ ml0, const float2* __restrict__ ml1)
{
    int i4 = blockIdx.x * 256 + threadIdx.x;   // float4 index, 2,097,152 total
    int i  = i4 * 4;
    int row = i >> 11;                          // / 2048
    int h   = (i >> 7) & 15;                    // / 128 % 16
    float2 a = ml0[row * HH + h];
    float2 c = ml1[row * HH + h];
    float M  = fmaxf(a.x, c.x);
    float e0 = __expf(a.x - M);
    float e1 = __expf(c.x - M);
    float inv = 1.0f / (e0 * a.y + e1 * c.y);
    float4 o0 = ((const float4*)out)[i4];
    float4 o1 = ((const float4*)wsO)[i4];
    float4 res;
    res.x = (e0 * o0.x + e1 * o1.x) * inv;
    res.y = (e0 * o0.y + e1 * o1.y) * inv;
    res.z = (e0 * o0.z + e1 * o1.z) * inv;
    res.w = (e0 * o0.w + e1 * o1.w) * inv;
    ((float4*)out)[i4] = res;
}

extern "C" void kernel_launch(void* const* d_in, const int* in_sizes, int n_in,
                              void* d_out, int out_size, void* d_ws, size_t ws_size,
                              hipStream_t stream) {
    const float* q = (const float*)d_in[0];
    const float* k = (const float*)d_in[1];
    const float* v = (const float*)d_in[2];
    float* out = (float*)d_out;
    // ws layout: [O_half1: 4096*2048 f32 = 32MB][ml0: 4096*16 float2][ml1: same]
    float*  wsO = (float*)d_ws;
    float2* ml0 = (float2*)((char*)d_ws + (size_t)SS * DM * 4);
    float2* ml1 = ml0 + SS * HH;
    fa_part<<<dim3(1024), dim3(256), 0, stream>>>(q, k, v, out, wsO, ml0, ml1);
    fa_merge<<<dim3(SS * DM / 4 / 256), dim3(256), 0, stream>>>(out, wsO, ml0, ml1);
}

// Round 4
// 292.641 us; speedup vs baseline: 1.6154x; 1.6154x over previous
//
#include <hip/hip_runtime.h>

#define HH 16
#define SS 4096
#define DHD 128
#define BR 64         // q rows per block (16 per wave)
#define BC 64         // k/v rows per tile
#define LDQ 144       // bf16/row for qp_s,k_s: 288B (16B-aligned, 4-way banks on b128)
#define LDV 68        // bf16/row for vt_s: 136B (b64 access, ~4-way)
#define LDPT 72       // bf16/row for pT_s: 144B (16B-aligned)
#define LDOS 136      // f32/row for epilogue overlay: 544B (16B-aligned)
#define DM  (HH * DHD)

typedef __bf16 bf16x8_t __attribute__((ext_vector_type(8)));
typedef __bf16 bf16x4_t __attribute__((ext_vector_type(4)));
typedef float  f32x4_t  __attribute__((ext_vector_type(4)));

// LDS-only barrier: drain lgkmcnt but leave global prefetch loads in flight
// (plain __syncthreads emits s_waitcnt vmcnt(0) which kills the prefetch).
#define BAR() asm volatile("s_waitcnt lgkmcnt(0)\n\ts_barrier" ::: "memory")

__device__ __forceinline__ f32x4_t vmax4(f32x4_t a, f32x4_t b) {
    f32x4_t r;
    r[0] = fmaxf(a[0], b[0]); r[1] = fmaxf(a[1], b[1]);
    r[2] = fmaxf(a[2], b[2]); r[3] = fmaxf(a[3], b[3]);
    return r;
}

__global__ __launch_bounds__(256, 2)
void fa_fwd(const float* __restrict__ q, const float* __restrict__ k,
            const float* __restrict__ v, float* __restrict__ out)
{
    // 512 equal blocks: q-tile pair {g, 63-g} -> 65 k-iters each (R2 scheduling).
    const int L = blockIdx.x;
    const int h = L & 15;
    const int g = L >> 4;
    const int qts[2] = { g, 63 - g };

    const int tid  = threadIdx.x;
    const int wave = tid >> 6;
    const int lane = tid & 63;
    const int l16  = lane & 15;
    const int quad = lane >> 4;
    const int rK   = tid >> 5;
    const int c4   = tid & 31;
    const int dbase = (wave & 1) * 64;
    const int rbase = (wave >> 1) * 32;

    // smem layout: [qp 18432][k 18432][vt 17408][pT 9216] = 63488 B
    __shared__ __align__(16) char smem[63488];
    unsigned short* qp_s = (unsigned short*)smem;
    unsigned short* k_s  = (unsigned short*)(smem + 18432);
    unsigned short* vt_s = (unsigned short*)(smem + 36864);
    unsigned short* pT_s = (unsigned short*)(smem + 54272);
    float* os = (float*)smem;   // epilogue overlay (34816 B over qp+k)

    const size_t hoff = (size_t)h * SS * DHD;
    const float* qh = q + hoff;
    const float* kh = k + hoff;
    const float* vh = v + hoff;

    float4 kreg[8];
    float  vreg[8][4];
    auto issue = [&](int j) {
        const float* kb = kh + (size_t)j * BC * DHD;
        #pragma unroll
        for (int i = 0; i < 8; ++i)
            kreg[i] = ((const float4*)(kb + (size_t)(rK + i * 8) * DHD))[c4];
        const float* vb = vh + (size_t)j * BC * DHD + dbase + lane;
        #pragma unroll
        for (int p = 0; p < 8; ++p) {
            const float* vp = vb + (size_t)(rbase + p * 4) * DHD;
            vreg[p][0] = vp[0];
            vreg[p][1] = vp[DHD];
            vreg[p][2] = vp[2 * DHD];
            vreg[p][3] = vp[3 * DHD];
        }
    };

    const float scale = 0.088388347648318447f;   // 1/sqrt(128), folded into Q
    issue(0);

    for (int t = 0; t < 2; ++t) {
        const int qt = qts[t];
        __syncthreads();               // prev tile's os reads done
        // ---- stage Q (scale folded) ----
        #pragma unroll
        for (int i = 0; i < 8; ++i) {
            int idx = tid + i * 256;
            int r   = idx >> 5;
            int cc  = idx & 31;
            float4 val = ((const float4*)(qh + (size_t)(qt * BR + r) * DHD))[cc];
            bf16x4_t bb;
            bb[0] = (__bf16)(val.x * scale); bb[1] = (__bf16)(val.y * scale);
            bb[2] = (__bf16)(val.z * scale); bb[3] = (__bf16)(val.w * scale);
            *(bf16x4_t*)&qp_s[r * LDQ + cc * 4] = bb;
        }
        __syncthreads();

        // ---- Q B-fragments (n-dim = wave's 16 q rows) ----
        bf16x8_t qf[4];
        #pragma unroll
        for (int kc = 0; kc < 4; ++kc)
            qf[kc] = *(const bf16x8_t*)
                &qp_s[(wave * 16 + l16) * LDQ + kc * 32 + quad * 8];

        f32x4_t oacc[8];               // O^T: row=d (8 m-tiles), col=q=l16
        #pragma unroll
        for (int mt = 0; mt < 8; ++mt) oacc[mt] = (f32x4_t)(0.0f);
        float mi = -INFINITY, li = 0.0f;   // per-lane scalars (one q per lane)

        const int q_local = wave * 16 + l16;

        for (int j = 0; j <= qt; ++j) {
            BAR();                     // prev-iter LDS reads drained; vm stays in flight
            // ---- commit prefetched K / V^T ----
            #pragma unroll
            for (int i = 0; i < 8; ++i) {
                bf16x4_t bb;
                bb[0] = (__bf16)kreg[i].x; bb[1] = (__bf16)kreg[i].y;
                bb[2] = (__bf16)kreg[i].z; bb[3] = (__bf16)kreg[i].w;
                *(bf16x4_t*)&k_s[(rK + i * 8) * LDQ + c4 * 4] = bb;
            }
            #pragma unroll
            for (int p = 0; p < 8; ++p) {
                bf16x4_t bb;
                bb[0] = (__bf16)vreg[p][0]; bb[1] = (__bf16)vreg[p][1];
                bb[2] = (__bf16)vreg[p][2]; bb[3] = (__bf16)vreg[p][3];
                *(bf16x4_t*)&vt_s[(dbase + lane) * LDV + rbase + p * 4] = bb;
            }
            if (j < qt)      issue(j + 1);
            else if (t == 0) issue(0);
            BAR();

            // ---- S^T = K Q^T : 4 m-tiles (k-dim) x 1 n-tile (q) ----
            f32x4_t sa[4];
            #pragma unroll
            for (int mt = 0; mt < 4; ++mt) sa[mt] = (f32x4_t)(0.0f);
            #pragma unroll
            for (int kc = 0; kc < 4; ++kc)
                #pragma unroll
                for (int mt = 0; mt < 4; ++mt) {
                    bf16x8_t kf = *(const bf16x8_t*)
                        &k_s[(mt * 16 + l16) * LDQ + kc * 32 + quad * 8];
                    sa[mt] = __builtin_amdgcn_mfma_f32_16x16x32_bf16(kf, qf[kc], sa[mt], 0, 0, 0);
                }

            // ---- causal mask (diag tile only): row=k=mt*16+quad*4+r, col=q=l16 ----
            if (j == qt) {
                #pragma unroll
                for (int mt = 0; mt < 4; ++mt)
                    #pragma unroll
                    for (int r = 0; r < 4; ++r)
                        if (mt * 16 + quad * 4 + r > q_local) sa[mt][r] = -INFINITY;
            }

            // ---- online softmax: in-lane 16 + 2 shfls ----
            f32x4_t mv = vmax4(vmax4(sa[0], sa[1]), vmax4(sa[2], sa[3]));
            float mx = fmaxf(fmaxf(mv[0], mv[1]), fmaxf(mv[2], mv[3]));
            mx = fmaxf(mx, __shfl_xor(mx, 16));
            mx = fmaxf(mx, __shfl_xor(mx, 32));
            float mnew = fmaxf(mi, mx);
            float a = __expf(mi - mnew);
            mi = mnew;
            bf16x4_t pkv[4];
            #pragma unroll
            for (int mt = 0; mt < 4; ++mt) {
                #pragma unroll
                for (int r = 0; r < 4; ++r) sa[mt][r] = __expf(sa[mt][r] - mnew);
                pkv[mt][0] = (__bf16)sa[mt][0]; pkv[mt][1] = (__bf16)sa[mt][1];
                pkv[mt][2] = (__bf16)sa[mt][2]; pkv[mt][3] = (__bf16)sa[mt][3];
            }
            f32x4_t sv = sa[0] + sa[1] + sa[2] + sa[3];
            float rs = (sv[0] + sv[1]) + (sv[2] + sv[3]);
            rs += __shfl_xor(rs, 16);
            rs += __shfl_xor(rs, 32);
            li = li * a + rs;

            // ---- P (q-major) -> LDS: 4 x ds_write_b64, wave-local ----
            #pragma unroll
            for (int mt = 0; mt < 4; ++mt)
                *(bf16x4_t*)&pT_s[(wave * 16 + l16) * LDPT + mt * 16 + quad * 4] = pkv[mt];

            // ---- rescale O^T by per-lane scalar alpha ----
            #pragma unroll
            for (int mt = 0; mt < 8; ++mt) {
                oacc[mt][0] *= a; oacc[mt][1] *= a;
                oacc[mt][2] *= a; oacc[mt][3] *= a;
            }

            // ---- O^T += V^T P^T : 8 m-tiles (d) x 1 n-tile (q), k=64 ----
            #pragma unroll
            for (int kc = 0; kc < 2; ++kc) {
                bf16x8_t pb = *(const bf16x8_t*)
                    &pT_s[(wave * 16 + l16) * LDPT + kc * 32 + quad * 8];
                #pragma unroll
                for (int mt = 0; mt < 8; ++mt) {
                    bf16x4_t vlo = *(const bf16x4_t*)
                        &vt_s[(mt * 16 + l16) * LDV + kc * 32 + quad * 8];
                    bf16x4_t vhi = *(const bf16x4_t*)
                        &vt_s[(mt * 16 + l16) * LDV + kc * 32 + quad * 8 + 4];
                    bf16x8_t vf = __builtin_shufflevector(vlo, vhi, 0,1,2,3,4,5,6,7);
                    oacc[mt] = __builtin_amdgcn_mfma_f32_16x16x32_bf16(vf, pb, oacc[mt], 0, 0, 0);
                }
            }
        }

        // ---- epilogue: O^T -> LDS overlay -> coalesced fp32 store ----
        __syncthreads();               // all frag reads done before overlay
        float inv = 1.0f / li;
        #pragma unroll
        for (int mt = 0; mt < 8; ++mt)
            #pragma unroll
            for (int r = 0; r < 4; ++r)
                os[(wave * 16 + l16) * LDOS + mt * 16 + quad * 4 + r] = oacc[mt][r] * inv;
        __syncthreads();
        #pragma unroll
        for (int p = 0; p < 8; ++p) {
            int row = p * 8 + rK;
            float4 f4 = *(const float4*)&os[row * LDOS + c4 * 4];
            *(float4*)&out[(size_t)(qt * BR + row) * DM + h * DHD + c4 * 4] = f4;
        }
    }
}

extern "C" void kernel_launch(void* const* d_in, const int* in_sizes, int n_in,
                              void* d_out, int out_size, void* d_ws, size_t ws_size,
                              hipStream_t stream) {
    const float* q = (const float*)d_in[0];
    const float* k = (const float*)d_in[1];
    const float* v = (const float*)d_in[2];
    float* out = (float*)d_out;
    fa_fwd<<<dim3((SS / BR / 2) * HH), dim3(256), 0, stream>>>(q, k, v, out);
}